// Round 1
// baseline (167.675 us; speedup 1.0000x reference)
//
#include <hip/hip_runtime.h>

// HyperLayer: N samples, K=4 real indices (2 input dims, 2 output dims).
// Factorized form: the 16 floor/ceil combos split as (dims 0,1) x (dims 2,3):
//   y[col(c,d)] += w2(c)*w3(d) * val * bilerp(x; idx0, idx1)
// -> 4 gathers + 4 atomics per sample instead of 16+16.

#define IN_DIM  1024
#define OUT_DIM 1024

__global__ __launch_bounds__(256) void HyperLayer_87746181857565_kernel(
    const float*  __restrict__ x,        // [1024*1024]
    const float4* __restrict__ ri,       // [N] (4 floats per sample, contiguous)
    const float*  __restrict__ vals,     // [N]
    float*        __restrict__ y,        // [1024*1024], pre-zeroed
    int n)
{
    int i = blockIdx.x * blockDim.x + threadIdx.x;
    if (i >= n) return;

    float4 r = ri[i];
    float val = vals[i];

    // floor/ceil per dim; weights exactly as reference: 1 - |int - real|.
    // When real is integral, floor==ceil and BOTH weights are 1 (reference
    // double-counts that point) — this form reproduces it.
    float f0 = floorf(r.x), c0 = ceilf(r.x);
    float f1 = floorf(r.y), c1 = ceilf(r.y);
    float f2 = floorf(r.z), c2 = ceilf(r.z);
    float f3 = floorf(r.w), c3 = ceilf(r.w);

    float wf0 = 1.0f - (r.x - f0), wc0 = 1.0f - (c0 - r.x);
    float wf1 = 1.0f - (r.y - f1), wc1 = 1.0f - (c1 - r.y);
    float wf2 = 1.0f - (r.z - f2), wc2 = 1.0f - (c2 - r.z);
    float wf3 = 1.0f - (r.w - f3), wc3 = 1.0f - (c3 - r.w);

    int if0 = (int)f0, ic0 = (int)c0;
    int if1 = (int)f1, ic1 = (int)c1;
    int if2 = (int)f2, ic2 = (int)c2;
    int if3 = (int)f3, ic3 = (int)c3;

    // Bilinear gather from x over dims 0,1 (x is 4 MB -> L2/L3 resident).
    const float* xr0 = x + if0 * IN_DIM;
    const float* xr1 = x + ic0 * IN_DIM;
    float s = wf0 * (wf1 * xr0[if1] + wc1 * xr0[ic1])
            + wc0 * (wf1 * xr1[if1] + wc1 * xr1[ic1]);
    s *= val;

    // Scatter over dims 2,3.
    float* y2 = y + if2 * OUT_DIM;
    float* y3 = y + ic2 * OUT_DIM;
    atomicAdd(y2 + if3, wf2 * wf3 * s);
    atomicAdd(y2 + ic3, wf2 * wc3 * s);
    atomicAdd(y3 + if3, wc2 * wf3 * s);
    atomicAdd(y3 + ic3, wc2 * wc3 * s);
}

extern "C" void kernel_launch(void* const* d_in, const int* in_sizes, int n_in,
                              void* d_out, int out_size, void* d_ws, size_t ws_size,
                              hipStream_t stream) {
    const float*  x    = (const float*)d_in[0];
    const float4* ri   = (const float4*)d_in[1];  // [N,4] f32, 16B-aligned
    const float*  vals = (const float*)d_in[2];
    float*        y    = (float*)d_out;
    int n = in_sizes[2];  // N = 500000

    // Harness poisons d_out with 0xAA before every call — zero it.
    hipMemsetAsync(y, 0, (size_t)out_size * sizeof(float), stream);

    int block = 256;
    int grid = (n + block - 1) / block;
    HyperLayer_87746181857565_kernel<<<grid, block, 0, stream>>>(x, ri, vals, y, n);
}

// Round 2
// 166.849 us; speedup vs baseline: 1.0050x; 1.0050x over previous
//
#include <hip/hip_runtime.h>

// HyperLayer: N samples, K=4 real indices (2 input dims, 2 output dims).
// Factorized form: the 16 floor/ceil combos split as (dims 0,1) x (dims 2,3):
//   y[col(c,d)] += w2(c)*w3(d) * val * bilerp(x; idx0, idx1)
// -> 4 gathers + 4 atomics per sample instead of 16+16.
//
// R2: default atomicAdd(float*) compiles to a CAS loop (WRITE_SIZE showed
// 32 B/atomic write-through, 2M x 32B = 64 MB). unsafeAtomicAdd emits native
// fire-and-forget global_atomic_add_f32 (d_out is coarse-grained hipMalloc
// memory, so HW FP atomics are correct).

#define IN_DIM  1024
#define OUT_DIM 1024

__global__ __launch_bounds__(256) void HyperLayer_87746181857565_kernel(
    const float*  __restrict__ x,        // [1024*1024]
    const float4* __restrict__ ri,       // [N] (4 floats per sample, contiguous)
    const float*  __restrict__ vals,     // [N]
    float*        __restrict__ y,        // [1024*1024], pre-zeroed
    int n)
{
    int i = blockIdx.x * blockDim.x + threadIdx.x;
    if (i >= n) return;

    float4 r = ri[i];
    float val = vals[i];

    // floor/ceil per dim; weights exactly as reference: 1 - |int - real|.
    // When real is integral, floor==ceil and BOTH weights are 1 (reference
    // double-counts that point) — this form reproduces it.
    float f0 = floorf(r.x), c0 = ceilf(r.x);
    float f1 = floorf(r.y), c1 = ceilf(r.y);
    float f2 = floorf(r.z), c2 = ceilf(r.z);
    float f3 = floorf(r.w), c3 = ceilf(r.w);

    float wf0 = 1.0f - (r.x - f0), wc0 = 1.0f - (c0 - r.x);
    float wf1 = 1.0f - (r.y - f1), wc1 = 1.0f - (c1 - r.y);
    float wf2 = 1.0f - (r.z - f2), wc2 = 1.0f - (c2 - r.z);
    float wf3 = 1.0f - (r.w - f3), wc3 = 1.0f - (c3 - r.w);

    int if0 = (int)f0, ic0 = (int)c0;
    int if1 = (int)f1, ic1 = (int)c1;
    int if2 = (int)f2, ic2 = (int)c2;
    int if3 = (int)f3, ic3 = (int)c3;

    // Bilinear gather from x over dims 0,1 (x is 4 MB -> L2/L3 resident).
    const float* xr0 = x + if0 * IN_DIM;
    const float* xr1 = x + ic0 * IN_DIM;
    float s = wf0 * (wf1 * xr0[if1] + wc1 * xr0[ic1])
            + wc0 * (wf1 * xr1[if1] + wc1 * xr1[ic1]);
    s *= val;

    // Scatter over dims 2,3 — native HW FP atomics, no return value.
    float* y2 = y + if2 * OUT_DIM;
    float* y3 = y + ic2 * OUT_DIM;
    unsafeAtomicAdd(y2 + if3, wf2 * wf3 * s);
    unsafeAtomicAdd(y2 + ic3, wf2 * wc3 * s);
    unsafeAtomicAdd(y3 + if3, wc2 * wf3 * s);
    unsafeAtomicAdd(y3 + ic3, wc2 * wc3 * s);
}

extern "C" void kernel_launch(void* const* d_in, const int* in_sizes, int n_in,
                              void* d_out, int out_size, void* d_ws, size_t ws_size,
                              hipStream_t stream) {
    const float*  x    = (const float*)d_in[0];
    const float4* ri   = (const float4*)d_in[1];  // [N,4] f32, 16B-aligned
    const float*  vals = (const float*)d_in[2];
    float*        y    = (float*)d_out;
    int n = in_sizes[2];  // N = 500000

    // Harness poisons d_out with 0xAA before every call — zero it.
    hipMemsetAsync(y, 0, (size_t)out_size * sizeof(float), stream);

    int block = 256;
    int grid = (n + block - 1) / block;
    HyperLayer_87746181857565_kernel<<<grid, block, 0, stream>>>(x, ri, vals, y, n);
}

// Round 3
// 99.296 us; speedup vs baseline: 1.6887x; 1.6803x over previous
//
#include <hip/hip_runtime.h>

// HyperLayer, R3: two-phase binned scatter.
// R2 evidence: device-scope fp atomics execute memory-side (WRITE_SIZE ==
// 2M x 32 B exactly; 19 G atomics/s ceiling; VALUBusy 0.9%). Fix: move the
// 2M scatter-adds into LDS.
//   Phase 1: bin samples by output row-group (4 rows = 4096 floats per bin,
//            256 bins), dense per-bin record regions claimed via one global
//            atomic per (block,bin) (~63k atomics total). Record (16 B):
//            {colbase, u=w2a*s, v=w2b*s, w3enc} — exact f32. Integral
//            floor==ceil double-count folded into w2a / w3enc==2.0 encoding.
//            Samples whose row pair (if2, if2+1) straddles a bin emit two
//            records (second carries the w2b row, v=0).
//   Phase 2: one block per bin; ds_add_f32 into a 4-row LDS tile (+1 row +1
//            col margin absorbs weight-0 edge adds), then one coalesced
//            float4 write per element. Tiles cover y exactly -> no y memset.

#define IN_DIM   1024
#define OUT_COLS 1024
#define NBINS    256
#define CAP      4096                 // records per bin (expect ~2441, 12 sigma headroom)
#define SPB      2048                 // samples per phase-1 block
#define P1T      512                  // phase-1 threads
#define TILE_F   4096                 // 4 rows * 1024 cols
#define TILE_PAD (TILE_F + OUT_COLS + 8)   // margin: idx+1025 <= 5120 < 5128

__global__ __launch_bounds__(P1T) void hl_phase1(
    const float*  __restrict__ x,
    const float4* __restrict__ ri,
    const float*  __restrict__ vals,
    int4*         __restrict__ recbuf,   // [NBINS * CAP]
    int*          __restrict__ gctr,     // [NBINS], pre-zeroed
    int n)
{
    __shared__ int hist[NBINS];
    __shared__ int base[NBINS];
    __shared__ int cur[NBINS];
    const int tid = threadIdx.x;
    if (tid < NBINS) { hist[tid] = 0; cur[tid] = 0; }
    __syncthreads();

    const int i0 = blockIdx.x * SPB;

    // pass 1: count records per bin (needs only r.z)
    #pragma unroll
    for (int s = 0; s < SPB / P1T; ++s) {
        int i = i0 + s * P1T + tid;
        if (i < n) {
            float rz = ri[i].z;
            int if2 = (int)floorf(rz);
            int ic2 = (int)ceilf(rz);
            int b0 = if2 >> 2, b1 = ic2 >> 2;
            atomicAdd(&hist[b0], 1);
            if (b1 != b0) atomicAdd(&hist[b1], 1);
        }
    }
    __syncthreads();

    // claim dense per-bin regions: one global atomic per (block,bin)
    if (tid < NBINS) {
        int h = hist[tid];
        base[tid] = h ? atomicAdd(&gctr[tid], h) : 0;
    }
    __syncthreads();

    // pass 2: full compute + emit records
    #pragma unroll
    for (int s = 0; s < SPB / P1T; ++s) {
        int i = i0 + s * P1T + tid;
        if (i >= n) continue;
        float4 r  = ri[i];
        float val = vals[i];

        float f0 = floorf(r.x), c0 = ceilf(r.x);
        float f1 = floorf(r.y), c1 = ceilf(r.y);
        float f2 = floorf(r.z), c2 = ceilf(r.z);
        float f3 = floorf(r.w), c3 = ceilf(r.w);
        float wf0 = 1.f - (r.x - f0), wc0 = 1.f - (c0 - r.x);
        float wf1 = 1.f - (r.y - f1), wc1 = 1.f - (c1 - r.y);
        float wf2 = 1.f - (r.z - f2), wc2 = 1.f - (c2 - r.z);
        float wf3 = 1.f - (r.w - f3), wc3 = 1.f - (c3 - r.w);
        int if0=(int)f0, ic0=(int)c0, if1=(int)f1, ic1=(int)c1;
        int if2=(int)f2, ic2=(int)c2, if3=(int)f3, ic3=(int)c3;

        // bilinear gather over dims 0,1 (x is L2-resident)
        const float* xr0 = x + if0 * IN_DIM;
        const float* xr1 = x + ic0 * IN_DIM;
        float s_ = wf0 * (wf1 * xr0[if1] + wc1 * xr0[ic1])
                 + wc0 * (wf1 * xr1[if1] + wc1 * xr1[ic1]);
        s_ *= val;

        // merged row/col weights (integral case: both floor & ceil hit same cell)
        float w2a, w2b;
        if (ic2 == if2) { w2a = wf2 + wc2; w2b = 0.f; }
        else            { w2a = wf2;       w2b = wc2; }
        float w3enc = (ic3 == if3) ? 2.0f : wf3;   // decode: 2->(2,0), w->(w,1-w)

        int b0 = if2 >> 2, b1 = ic2 >> 2;
        {
            int rank = atomicAdd(&cur[b0], 1);
            int slot = base[b0] + rank;
            if (slot < CAP) {
                int4 rec;
                rec.x = if2 * OUT_COLS + if3;
                rec.y = __float_as_int(w2a * s_);
                rec.z = __float_as_int((b1 == b0) ? w2b * s_ : 0.f);
                rec.w = __float_as_int(w3enc);
                recbuf[b0 * CAP + slot] = rec;
            }
        }
        if (b1 != b0) {   // second row lands in next bin: emit its own record
            int rank = atomicAdd(&cur[b1], 1);
            int slot = base[b1] + rank;
            if (slot < CAP) {
                int4 rec;
                rec.x = ic2 * OUT_COLS + if3;
                rec.y = __float_as_int(w2b * s_);
                rec.z = __float_as_int(0.f);
                rec.w = __float_as_int(w3enc);
                recbuf[b1 * CAP + slot] = rec;
            }
        }
    }
}

__global__ __launch_bounds__(256) void hl_phase2(
    const int4* __restrict__ recbuf,
    const int*  __restrict__ gctr,
    float*      __restrict__ y)
{
    __shared__ __align__(16) float tile[TILE_PAD];
    const int bin = blockIdx.x;
    const int tid = threadIdx.x;
    for (int k = tid; k < TILE_PAD; k += 256) tile[k] = 0.f;
    __syncthreads();

    int count = gctr[bin];
    if (count > CAP) count = CAP;
    const int4* rb = recbuf + bin * CAP;
    const int tilebase = bin * TILE_F;

    for (int j = tid; j < count; j += 256) {
        int4 rec = rb[j];
        int   idx = rec.x - tilebase;
        float u   = __int_as_float(rec.y);
        float v   = __int_as_float(rec.z);
        float w3e = __int_as_float(rec.w);
        float w3a, w3b;
        if (w3e == 2.0f) { w3a = 2.0f; w3b = 0.f; }
        else             { w3a = w3e;  w3b = 1.0f - w3e; }
        __hip_atomic_fetch_add(&tile[idx],     u * w3a, __ATOMIC_RELAXED, __HIP_MEMORY_SCOPE_WORKGROUP);
        __hip_atomic_fetch_add(&tile[idx + 1], u * w3b, __ATOMIC_RELAXED, __HIP_MEMORY_SCOPE_WORKGROUP);
        if (v != 0.f) {
            __hip_atomic_fetch_add(&tile[idx + 1024], v * w3a, __ATOMIC_RELAXED, __HIP_MEMORY_SCOPE_WORKGROUP);
            __hip_atomic_fetch_add(&tile[idx + 1025], v * w3b, __ATOMIC_RELAXED, __HIP_MEMORY_SCOPE_WORKGROUP);
        }
    }
    __syncthreads();

    // tiles partition y exactly: plain coalesced stores, no memset needed
    float4* y4 = (float4*)y + bin * (TILE_F / 4);
    const float4* t4 = (const float4*)tile;
    for (int k = tid; k < TILE_F / 4; k += 256) y4[k] = t4[k];
}

// ---- fallback (ws too small): R1 direct-atomic kernel ----
__global__ __launch_bounds__(256) void hl_direct(
    const float* __restrict__ x, const float4* __restrict__ ri,
    const float* __restrict__ vals, float* __restrict__ y, int n)
{
    int i = blockIdx.x * blockDim.x + threadIdx.x;
    if (i >= n) return;
    float4 r = ri[i];
    float val = vals[i];
    float f0 = floorf(r.x), c0 = ceilf(r.x);
    float f1 = floorf(r.y), c1 = ceilf(r.y);
    float f2 = floorf(r.z), c2 = ceilf(r.z);
    float f3 = floorf(r.w), c3 = ceilf(r.w);
    float wf0 = 1.f-(r.x-f0), wc0 = 1.f-(c0-r.x);
    float wf1 = 1.f-(r.y-f1), wc1 = 1.f-(c1-r.y);
    float wf2 = 1.f-(r.z-f2), wc2 = 1.f-(c2-r.z);
    float wf3 = 1.f-(r.w-f3), wc3 = 1.f-(c3-r.w);
    int if0=(int)f0, ic0=(int)c0, if1=(int)f1, ic1=(int)c1;
    int if2=(int)f2, ic2=(int)c2, if3=(int)f3, ic3=(int)c3;
    const float* xr0 = x + if0 * IN_DIM;
    const float* xr1 = x + ic0 * IN_DIM;
    float s = wf0*(wf1*xr0[if1]+wc1*xr0[ic1]) + wc0*(wf1*xr1[if1]+wc1*xr1[ic1]);
    s *= val;
    float* y2 = y + if2 * OUT_COLS;
    float* y3 = y + ic2 * OUT_COLS;
    unsafeAtomicAdd(y2 + if3, wf2*wf3*s);
    unsafeAtomicAdd(y2 + ic3, wf2*wc3*s);
    unsafeAtomicAdd(y3 + if3, wc2*wf3*s);
    unsafeAtomicAdd(y3 + ic3, wc2*wc3*s);
}

extern "C" void kernel_launch(void* const* d_in, const int* in_sizes, int n_in,
                              void* d_out, int out_size, void* d_ws, size_t ws_size,
                              hipStream_t stream) {
    const float*  x    = (const float*)d_in[0];
    const float4* ri   = (const float4*)d_in[1];
    const float*  vals = (const float*)d_in[2];
    float*        y    = (float*)d_out;
    int n = in_sizes[2];  // N = 500000

    const size_t REQ = 1024 + (size_t)NBINS * CAP * sizeof(int4);  // ~16.8 MB
    if (ws_size >= REQ) {
        int*  gctr   = (int*)d_ws;
        int4* recbuf = (int4*)((char*)d_ws + 1024);
        hipMemsetAsync(d_ws, 0, 1024, stream);   // zero bin counters (ws poisoned each call)
        int grid1 = (n + SPB - 1) / SPB;
        hl_phase1<<<grid1, P1T, 0, stream>>>(x, ri, vals, recbuf, gctr, n);
        hl_phase2<<<NBINS, 256, 0, stream>>>(recbuf, gctr, y);
    } else {
        hipMemsetAsync(y, 0, (size_t)out_size * sizeof(float), stream);
        int grid = (n + 255) / 256;
        hl_direct<<<grid, 256, 0, stream>>>(x, ri, vals, y, n);
    }
}